// Round 3
// baseline (125.121 us; speedup 1.0000x reference)
//
#include <hip/hip_runtime.h>
#include <hip/hip_bf16.h>

typedef __bf16 bf16x8 __attribute__((ext_vector_type(8)));
typedef __bf16 bf16x4 __attribute__((ext_vector_type(4)));
typedef __bf16 bf16x2 __attribute__((ext_vector_type(2)));
typedef float  floatx4 __attribute__((ext_vector_type(4)));

static constexpr int TWO_B = 8192;   // 2*B rows
static constexpr int CDIM  = 128;    // feature dim
// exp(x/T) = exp2(x * (1/T)/ln2), T = 0.5
#define SCALE 2.8853900817779268f
#define INV_T 2.0f

#if __has_builtin(__builtin_amdgcn_exp2f)
#define EXP2F(x) __builtin_amdgcn_exp2f(x)
#else
#define EXP2F(x) exp2f(x)
#endif

// ---------------------------------------------------------------------------
// Kernel 1: L2-normalize rows; fp32 + bf16 copies. 32 lanes per row (float4),
// 8 rows per 256-thread block.
// ---------------------------------------------------------------------------
__global__ __launch_bounds__(256) void nk(const float* __restrict__ zi,
                                          const float* __restrict__ zj,
                                          float* __restrict__ nf,
                                          __bf16* __restrict__ nb) {
    const int l32 = threadIdx.x & 31;
    const int row = blockIdx.x * 8 + (threadIdx.x >> 5);
    const float* src = (row < 4096) ? (zi + row * CDIM) : (zj + (row - 4096) * CDIM);
    float4 x = reinterpret_cast<const float4*>(src)[l32];
    float ss = x.x * x.x + x.y * x.y + x.z * x.z + x.w * x.w;
#pragma unroll
    for (int m = 1; m < 32; m <<= 1) ss += __shfl_xor(ss, m, 64);  // masks <32 stay in half
    const float rn = rsqrtf(ss);
    float4 y; y.x = x.x * rn; y.y = x.y * rn; y.z = x.z * rn; y.w = x.w * rn;
    reinterpret_cast<float4*>(nf + row * CDIM)[l32] = y;
    bf16x4 b; b[0] = (__bf16)y.x; b[1] = (__bf16)y.y; b[2] = (__bf16)y.z; b[3] = (__bf16)y.w;
    reinterpret_cast<bf16x4*>(nb + row * CDIM)[l32] = b;
}

// ---------------------------------------------------------------------------
// Kernel 2: per-row sum of exp(sim[r,j]/T) over a 512-column slice.
// Block = 256 thr (4 waves), 128 rows/block (wave w -> rows w*32..+32).
// Columns streamed in 128-wide stages (32 KB LDS) via global_load_lds (16B),
// XOR-swizzled so ds_read_b128 B-frag reads are 2-way max (free per m136).
// Grid: (64 row tiles, 16 column splits); partials per (split,row), no atomics.
// ---------------------------------------------------------------------------
__global__ __launch_bounds__(256) void sk(const __bf16* __restrict__ nb,
                                          float* __restrict__ partial) {
    const int rt  = blockIdx.x;   // 0..63
    const int csp = blockIdx.y;   // 0..15
    const int tid = threadIdx.x;
    const int w   = tid >> 6;
    const int lane = tid & 63;
    const int l15 = lane & 15;
    const int lg  = lane >> 4;

    __shared__ __bf16 ldsB[128 * CDIM];   // 32 KB

    // A fragments: 32 rows x 128 k per wave, kept in registers.
    // A-layout: m = lane&15, k = (lane>>4)*8 + j  (per 32-wide k-step)
    const int rowbase = rt * 128 + w * 32;
    bf16x8 afrag[2][4];
#pragma unroll
    for (int mi = 0; mi < 2; ++mi)
#pragma unroll
        for (int kq = 0; kq < 4; ++kq)
            afrag[mi][kq] = *reinterpret_cast<const bf16x8*>(
                nb + (rowbase + mi * 16 + l15) * CDIM + kq * 32 + lg * 8);

    float rowsum[2][4];
#pragma unroll
    for (int mi = 0; mi < 2; ++mi)
#pragma unroll
        for (int r = 0; r < 4; ++r) rowsum[mi][r] = 0.0f;

    const int colbase0 = csp * 512;
    for (int ct = 0; ct < 4; ++ct) {
        const int colbase = colbase0 + ct * 128;
        __syncthreads();   // previous stage's compute done before overwrite
        // Stage 128 rows x 256 B. LDS 16B-slot s <- global chunk
        // (R = s>>4, c = (s&15) ^ (R&15)) — XOR swizzle kills bank conflicts.
#pragma unroll
        for (int i = 0; i < 8; ++i) {
            const int s = i * 256 + tid;          // per-wave: uniform base + lane*16
            const int R = s >> 4, cs = s & 15;
            const int gc = cs ^ (R & 15);
            const __bf16* g = nb + (colbase + R) * CDIM + gc * 8;
            __builtin_amdgcn_global_load_lds(
                (__attribute__((address_space(1))) void*)g,
                (__attribute__((address_space(3))) void*)(ldsB + s * 8),
                16, 0, 0);
        }
        __syncthreads();   // vmcnt(0) drain before barrier

#pragma unroll
        for (int ni = 0; ni < 8; ++ni) {
            floatx4 acc0 = {0.f, 0.f, 0.f, 0.f};
            floatx4 acc1 = {0.f, 0.f, 0.f, 0.f};
#pragma unroll
            for (int kq = 0; kq < 4; ++kq) {
                // B-layout: n = lane&15 (local row R), k = (lane>>4)*8 + j
                const int R    = ni * 16 + l15;
                const int cg   = kq * 4 + lg;
                const int slot = R * 16 + (cg ^ (R & 15));
                bf16x8 bfrag = *reinterpret_cast<const bf16x8*>(ldsB + slot * 8);
                acc0 = __builtin_amdgcn_mfma_f32_16x16x32_bf16(afrag[0][kq], bfrag, acc0, 0, 0, 0);
                acc1 = __builtin_amdgcn_mfma_f32_16x16x32_bf16(afrag[1][kq], bfrag, acc1, 0, 0, 0);
            }
            // C/D layout: col = lane&15, row = (lane>>4)*4 + reg
#pragma unroll
            for (int r = 0; r < 4; ++r) {
                rowsum[0][r] += EXP2F(acc0[r] * SCALE);
                rowsum[1][r] += EXP2F(acc1[r] * SCALE);
            }
        }
    }

    // Sum across the 16 column-lanes within each lane-group.
#pragma unroll
    for (int mi = 0; mi < 2; ++mi)
#pragma unroll
        for (int r = 0; r < 4; ++r) {
            float v = rowsum[mi][r];
            v += __shfl_xor(v, 1, 64);
            v += __shfl_xor(v, 2, 64);
            v += __shfl_xor(v, 4, 64);
            v += __shfl_xor(v, 8, 64);
            rowsum[mi][r] = v;
        }
    if (l15 == 0) {
#pragma unroll
        for (int mi = 0; mi < 2; ++mi)
#pragma unroll
            for (int r = 0; r < 4; ++r)
                partial[csp * TWO_B + rowbase + mi * 16 + lg * 4 + r] = rowsum[mi][r];
    }
}

// ---------------------------------------------------------------------------
// Kernel 3: per-row finalize + fused mean. One wave per row:
//   pos   = fp32 dot(n_r, n_partner)          (exact positive logit)
//   selfd = ||bf16(n_r)||^2                   (matches MFMA's diagonal value)
//   S     = sum_c partial[c][row] + exp(pos/T) - exp(selfd/T)
//   loss_r = log(S) - pos/T
// Block-reduce 4 row losses, one atomicAdd into out (zeroed via memsetAsync).
// ---------------------------------------------------------------------------
__global__ __launch_bounds__(256) void fk(const float* __restrict__ nf,
                                          const __bf16* __restrict__ nb,
                                          const float* __restrict__ partial,
                                          float* __restrict__ out) {
    const int w = threadIdx.x >> 6, lane = threadIdx.x & 63;
    const int row = blockIdx.x * 4 + w;
    const int partner = (row + 4096) & (TWO_B - 1);
    float2 a = reinterpret_cast<const float2*>(nf + row * CDIM)[lane];
    float2 b = reinterpret_cast<const float2*>(nf + partner * CDIM)[lane];
    float dot = a.x * b.x + a.y * b.y;
    bf16x2 sb = reinterpret_cast<const bf16x2*>(nb + row * CDIM)[lane];
    const float s0 = (float)sb[0], s1 = (float)sb[1];
    float sq = s0 * s0 + s1 * s1;
    float ps = (lane < 16) ? partial[lane * TWO_B + row] : 0.0f;
#pragma unroll
    for (int m = 1; m < 64; m <<= 1) {
        dot += __shfl_xor(dot, m, 64);
        sq  += __shfl_xor(sq,  m, 64);
        ps  += __shfl_xor(ps,  m, 64);
    }
    __shared__ float ls[4];
    if (lane == 0) {
        const float S = ps + EXP2F(dot * SCALE) - EXP2F(sq * SCALE);
        ls[w] = __logf(S) - dot * INV_T;
    }
    __syncthreads();
    if (threadIdx.x == 0)
        atomicAdd(out, (ls[0] + ls[1] + ls[2] + ls[3]) * (1.0f / TWO_B));
}

extern "C" void kernel_launch(void* const* d_in, const int* in_sizes, int n_in,
                              void* d_out, int out_size, void* d_ws, size_t ws_size,
                              hipStream_t stream) {
    const float* zi = (const float*)d_in[0];
    const float* zj = (const float*)d_in[1];
    char* ws = (char*)d_ws;
    float*  nf      = (float*)ws;                                  // 8192*128 f32 = 4 MB
    __bf16* nb      = (__bf16*)(ws + (size_t)TWO_B * CDIM * 4);    // 8192*128 bf16 = 2 MB
    float*  partial = (float*)(ws + (size_t)TWO_B * CDIM * 6);     // 16*8192 f32 = 512 KB

    hipMemsetAsync(d_out, 0, sizeof(float), stream);
    nk<<<TWO_B / 8, 256, 0, stream>>>(zi, zj, nf, nb);
    sk<<<dim3(64, 16), 256, 0, stream>>>(nb, partial);
    fk<<<TWO_B / 4, 256, 0, stream>>>(nf, nb, partial, (float*)d_out);
}

// Round 4
// 104.477 us; speedup vs baseline: 1.1976x; 1.1976x over previous
//
#include <hip/hip_runtime.h>
#include <hip/hip_bf16.h>

typedef __bf16 bf16x8 __attribute__((ext_vector_type(8)));
typedef __bf16 bf16x4 __attribute__((ext_vector_type(4)));
typedef __bf16 bf16x2 __attribute__((ext_vector_type(2)));
typedef float  floatx4 __attribute__((ext_vector_type(4)));

static constexpr int TWO_B = 8192;   // 2*B rows
static constexpr int CDIM  = 128;    // feature dim
// exp(x/T) = exp2(x * (1/T)/ln2), T = 0.5
#define SCALE 2.8853900817779268f
#define INV_T 2.0f

#if __has_builtin(__builtin_amdgcn_exp2f)
#define EXP2F(x) __builtin_amdgcn_exp2f(x)
#else
#define EXP2F(x) exp2f(x)
#endif

// ---------------------------------------------------------------------------
// Kernel 1: L2-normalize rows; fp32 + bf16 copies. 32 lanes per row (float4),
// 8 rows per 256-thread block.
// ---------------------------------------------------------------------------
__global__ __launch_bounds__(256) void nk(const float* __restrict__ zi,
                                          const float* __restrict__ zj,
                                          float* __restrict__ nf,
                                          __bf16* __restrict__ nb) {
    const int l32 = threadIdx.x & 31;
    const int row = blockIdx.x * 8 + (threadIdx.x >> 5);
    const float* src = (row < 4096) ? (zi + row * CDIM) : (zj + (row - 4096) * CDIM);
    float4 x = reinterpret_cast<const float4*>(src)[l32];
    float ss = x.x * x.x + x.y * x.y + x.z * x.z + x.w * x.w;
#pragma unroll
    for (int m = 1; m < 32; m <<= 1) ss += __shfl_xor(ss, m, 64);
    const float rn = rsqrtf(ss);
    float4 y; y.x = x.x * rn; y.y = x.y * rn; y.z = x.z * rn; y.w = x.w * rn;
    reinterpret_cast<float4*>(nf + row * CDIM)[l32] = y;
    bf16x4 b; b[0] = (__bf16)y.x; b[1] = (__bf16)y.y; b[2] = (__bf16)y.z; b[3] = (__bf16)y.w;
    reinterpret_cast<bf16x4*>(nb + row * CDIM)[l32] = b;
}

// ---------------------------------------------------------------------------
// Kernel 2: per-row sum of exp(sim[r,j]/T) over a 512-column slice.
// Block = 256 thr (4 waves), 256 rows/block: wave w owns rows w*64..+64
// (FOUR 16-row m-subtiles -> each B-frag ds_read_b128 feeds 4 MFMAs,
// halving LDS-read traffic vs 2-subtile version; LDS pipe was the modeled
// bottleneck at 6.8 us/CU). Columns streamed in 64-wide stages (16 KB LDS)
// via global_load_lds (16B), XOR-swizzled -> exactly 8 words/bank per b128
// (optimal). Grid: (32 row tiles, 16 column splits); partials per
// (split,row), no atomics.
// ---------------------------------------------------------------------------
__global__ __launch_bounds__(256) void sk(const __bf16* __restrict__ nb,
                                          float* __restrict__ partial) {
    const int rt  = blockIdx.x;   // 0..31
    const int csp = blockIdx.y;   // 0..15
    const int tid = threadIdx.x;
    const int w   = tid >> 6;
    const int lane = tid & 63;
    const int l15 = lane & 15;
    const int lg  = lane >> 4;

    __shared__ __bf16 ldsB[64 * CDIM];   // 16 KB

    // A fragments: 64 rows x 128 k per wave, kept in registers.
    // A-layout: m = lane&15, k = (lane>>4)*8 + j  (per 32-wide k-step)
    const int rowbase = rt * 256 + w * 64;
    bf16x8 afrag[4][4];
#pragma unroll
    for (int mi = 0; mi < 4; ++mi)
#pragma unroll
        for (int kq = 0; kq < 4; ++kq)
            afrag[mi][kq] = *reinterpret_cast<const bf16x8*>(
                nb + (rowbase + mi * 16 + l15) * CDIM + kq * 32 + lg * 8);

    float rowsum[4][4];
#pragma unroll
    for (int mi = 0; mi < 4; ++mi)
#pragma unroll
        for (int r = 0; r < 4; ++r) rowsum[mi][r] = 0.0f;

    const int colbase0 = csp * 512;
    for (int ct = 0; ct < 8; ++ct) {
        const int colbase = colbase0 + ct * 64;
        __syncthreads();   // previous stage's compute done before overwrite
        // Stage 64 rows x 256 B. LDS 16B-slot s <- global chunk
        // (R = s>>4, c = (s&15) ^ (R&15)) — XOR swizzle spreads banks.
#pragma unroll
        for (int i = 0; i < 4; ++i) {
            const int s = i * 256 + tid;          // per-wave: uniform base + lane*16
            const int R = s >> 4, cs = s & 15;
            const int gc = cs ^ (R & 15);
            const __bf16* g = nb + (colbase + R) * CDIM + gc * 8;
            __builtin_amdgcn_global_load_lds(
                (__attribute__((address_space(1))) void*)g,
                (__attribute__((address_space(3))) void*)(ldsB + s * 8),
                16, 0, 0);
        }
        __syncthreads();   // vmcnt(0) drain before barrier

#pragma unroll
        for (int ni = 0; ni < 4; ++ni) {
            floatx4 acc[4];
#pragma unroll
            for (int mi = 0; mi < 4; ++mi) acc[mi] = floatx4{0.f, 0.f, 0.f, 0.f};
#pragma unroll
            for (int kq = 0; kq < 4; ++kq) {
                // B-layout: n = lane&15 (local row R), k = (lane>>4)*8 + j
                const int R    = ni * 16 + l15;
                const int cg   = kq * 4 + lg;
                const int slot = R * 16 + (cg ^ (R & 15));
                bf16x8 bfrag = *reinterpret_cast<const bf16x8*>(ldsB + slot * 8);
#pragma unroll
                for (int mi = 0; mi < 4; ++mi)
                    acc[mi] = __builtin_amdgcn_mfma_f32_16x16x32_bf16(
                        afrag[mi][kq], bfrag, acc[mi], 0, 0, 0);
            }
            // C/D layout: col = lane&15, row = (lane>>4)*4 + reg
#pragma unroll
            for (int mi = 0; mi < 4; ++mi)
#pragma unroll
                for (int r = 0; r < 4; ++r)
                    rowsum[mi][r] += EXP2F(acc[mi][r] * SCALE);
        }
    }

    // Sum across the 16 column-lanes within each lane-group.
#pragma unroll
    for (int mi = 0; mi < 4; ++mi)
#pragma unroll
        for (int r = 0; r < 4; ++r) {
            float v = rowsum[mi][r];
            v += __shfl_xor(v, 1, 64);
            v += __shfl_xor(v, 2, 64);
            v += __shfl_xor(v, 4, 64);
            v += __shfl_xor(v, 8, 64);
            rowsum[mi][r] = v;
        }
    if (l15 == 0) {
#pragma unroll
        for (int mi = 0; mi < 4; ++mi)
#pragma unroll
            for (int r = 0; r < 4; ++r)
                partial[csp * TWO_B + rowbase + mi * 16 + lg * 4 + r] = rowsum[mi][r];
    }
}

// ---------------------------------------------------------------------------
// Kernel 3: per-row finalize. One wave per row (non-atomic — R3's 2048-way
// single-address atomic fan-in cost ~20 us):
//   pos   = fp32 dot(n_r, n_partner)          (exact positive logit)
//   selfd = ||bf16(n_r)||^2                   (matches MFMA's diagonal value)
//   S     = sum_c partial[c][row] + exp(pos/T) - exp(selfd/T)
//   loss_r = log(S) - pos/T
// ---------------------------------------------------------------------------
__global__ __launch_bounds__(256) void fk(const float* __restrict__ nf,
                                          const __bf16* __restrict__ nb,
                                          const float* __restrict__ partial,
                                          float* __restrict__ rowloss) {
    const int w = threadIdx.x >> 6, lane = threadIdx.x & 63;
    const int row = blockIdx.x * 4 + w;
    const int partner = (row + 4096) & (TWO_B - 1);
    float2 a = reinterpret_cast<const float2*>(nf + row * CDIM)[lane];
    float2 b = reinterpret_cast<const float2*>(nf + partner * CDIM)[lane];
    float dot = a.x * b.x + a.y * b.y;
    bf16x2 sb = reinterpret_cast<const bf16x2*>(nb + row * CDIM)[lane];
    const float s0 = (float)sb[0], s1 = (float)sb[1];
    float sq = s0 * s0 + s1 * s1;
    float ps = (lane < 16) ? partial[lane * TWO_B + row] : 0.0f;
#pragma unroll
    for (int m = 1; m < 64; m <<= 1) {
        dot += __shfl_xor(dot, m, 64);
        sq  += __shfl_xor(sq,  m, 64);
        ps  += __shfl_xor(ps,  m, 64);
    }
    if (lane == 0) {
        const float S = ps + EXP2F(dot * SCALE) - EXP2F(sq * SCALE);
        rowloss[row] = __logf(S) - dot * INV_T;
    }
}

// ---------------------------------------------------------------------------
// Kernel 4: mean over 8192 row losses -> fp32 scalar.
// ---------------------------------------------------------------------------
__global__ __launch_bounds__(256) void rk(const float* __restrict__ rowloss,
                                          float* __restrict__ out) {
    const int tid = threadIdx.x;
    float s = 0.f;
    for (int i = tid; i < TWO_B; i += 256) s += rowloss[i];
#pragma unroll
    for (int m = 1; m < 64; m <<= 1) s += __shfl_xor(s, m, 64);
    __shared__ float acc[4];
    if ((tid & 63) == 0) acc[tid >> 6] = s;
    __syncthreads();
    if (tid == 0)
        out[0] = (acc[0] + acc[1] + acc[2] + acc[3]) * (1.0f / TWO_B);
}

extern "C" void kernel_launch(void* const* d_in, const int* in_sizes, int n_in,
                              void* d_out, int out_size, void* d_ws, size_t ws_size,
                              hipStream_t stream) {
    const float* zi = (const float*)d_in[0];
    const float* zj = (const float*)d_in[1];
    char* ws = (char*)d_ws;
    float*  nf      = (float*)ws;                                  // 8192*128 f32 = 4 MB
    __bf16* nb      = (__bf16*)(ws + (size_t)TWO_B * CDIM * 4);    // 8192*128 bf16 = 2 MB
    float*  partial = (float*)(ws + (size_t)TWO_B * CDIM * 6);     // 16*8192 f32 = 512 KB
    float*  rowloss = (float*)(ws + (size_t)TWO_B * CDIM * 6 + (size_t)16 * TWO_B * 4);

    nk<<<TWO_B / 8, 256, 0, stream>>>(zi, zj, nf, nb);
    sk<<<dim3(32, 16), 256, 0, stream>>>(nb, partial);
    fk<<<TWO_B / 4, 256, 0, stream>>>(nf, nb, partial, rowloss);
    rk<<<1, 256, 0, stream>>>(rowloss, (float*)d_out);
}

// Round 5
// 88.203 us; speedup vs baseline: 1.4186x; 1.1845x over previous
//
#include <hip/hip_runtime.h>
#include <hip/hip_bf16.h>

typedef int   intx8   __attribute__((ext_vector_type(8)));
typedef int   intx4   __attribute__((ext_vector_type(4)));
typedef float floatx4 __attribute__((ext_vector_type(4)));

static constexpr int TWO_B = 8192;   // 2*B rows
static constexpr int CDIM  = 128;    // feature dim
// exp(x/T) = exp2(x * (1/T)/ln2), T = 0.5
#define SCALE 2.8853900817779268f
#define SQS   1.6986436f             // sqrt(SCALE): n8 rows pre-scaled by this,
                                     // so MFMA output is already in exp2 domain
#define INV_T 2.0f

#if __has_builtin(__builtin_amdgcn_exp2f)
#define EXP2F(x) __builtin_amdgcn_exp2f(x)
#else
#define EXP2F(x) exp2f(x)
#endif

// e8m0 scale byte 0x7F = 2^0 = 1.0 in all four byte slots
#define SCL1 0x7F7F7F7F

// ---------------------------------------------------------------------------
// Kernel 1: L2-normalize rows. Writes fp32 copy (for exact positive logits)
// and fp8-e4m3 copy pre-scaled by sqrt(SCALE) (for the MX MFMA Gram kernel).
// 32 lanes per row (float4), 8 rows per block.
// ---------------------------------------------------------------------------
__global__ __launch_bounds__(256) void nk(const float* __restrict__ zi,
                                          const float* __restrict__ zj,
                                          float* __restrict__ nf,
                                          unsigned char* __restrict__ n8) {
    const int l32 = threadIdx.x & 31;
    const int row = blockIdx.x * 8 + (threadIdx.x >> 5);
    const float* src = (row < 4096) ? (zi + row * CDIM) : (zj + (row - 4096) * CDIM);
    float4 x = reinterpret_cast<const float4*>(src)[l32];
    float ss = x.x * x.x + x.y * x.y + x.z * x.z + x.w * x.w;
#pragma unroll
    for (int m = 1; m < 32; m <<= 1) ss += __shfl_xor(ss, m, 64);
    const float rn = rsqrtf(ss);
    float4 y; y.x = x.x * rn; y.y = x.y * rn; y.z = x.z * rn; y.w = x.w * rn;
    reinterpret_cast<float4*>(nf + row * CDIM)[l32] = y;
    const float s = SQS * rn;
    int p = __builtin_amdgcn_cvt_pk_fp8_f32(x.x * s, x.y * s, 0, false);
    p     = __builtin_amdgcn_cvt_pk_fp8_f32(x.z * s, x.w * s, p, true);
    reinterpret_cast<int*>(n8 + row * CDIM)[l32] = p;
}

// ---------------------------------------------------------------------------
// Kernel 2: per-row sum of 2^(SCALE*sim) over a 512-column slice, via
// MX-scaled fp8 MFMA (K=128 in ONE instruction, scales = 1.0; inputs carry
// sqrt(SCALE) so D = SCALE*sim directly -> exp2 with no mul).
// Block = 256 thr (4 waves), 256 rows/block (wave w -> rows w*64..+64,
// 4 m-subtiles; each B-frag feeds 4 MFMAs). Columns streamed in 64-wide
// stages (8 KB LDS) via global_load_lds 16B, global-side XOR swizzle ->
// exactly 8 touches/bank per ds_read_b128 (the wave64 minimum).
// Grid (32,16); partials per (split,row); no atomics.
// ---------------------------------------------------------------------------
__global__ __launch_bounds__(256) void sk(const unsigned char* __restrict__ n8,
                                          float* __restrict__ partial) {
    const int rt  = blockIdx.x;   // 0..31
    const int csp = blockIdx.y;   // 0..15
    const int tid = threadIdx.x;
    const int w   = tid >> 6;
    const int lane = tid & 63;
    const int l15 = lane & 15;
    const int lg  = lane >> 4;

    __shared__ unsigned char ldsB[64 * CDIM];   // 8 KB (fp8)

    // A fragments: 64 rows x 128 k per wave, registers.
    // f8f6f4 16x16x128 A-layout: m = lane&15, k = (lane>>4)*32 + j, j in [0,32)
    const int rowbase = rt * 256 + w * 64;
    intx8 afrag[4];
#pragma unroll
    for (int mi = 0; mi < 4; ++mi)
        afrag[mi] = *reinterpret_cast<const intx8*>(
            n8 + (rowbase + mi * 16 + l15) * CDIM + lg * 32);

    float rowsum[4][4];
#pragma unroll
    for (int mi = 0; mi < 4; ++mi)
#pragma unroll
        for (int r = 0; r < 4; ++r) rowsum[mi][r] = 0.0f;

    const int colbase0 = csp * 512;
    for (int ct = 0; ct < 8; ++ct) {
        const int colbase = colbase0 + ct * 64;
        __syncthreads();   // previous stage's compute done before overwrite
        // Stage 64 rows x 128 B. LDS 16B-slot s holds global chunk
        // (R = s>>3, c = (s&7) ^ (R&7)) — swizzle on the global side.
#pragma unroll
        for (int i = 0; i < 2; ++i) {
            const int s = i * 256 + tid;          // uniform base + lane*16
            const int R = s >> 3, cs = s & 7;
            const int gc = cs ^ (R & 7);
            const unsigned char* g = n8 + (colbase + R) * CDIM + gc * 16;
            __builtin_amdgcn_global_load_lds(
                (__attribute__((address_space(1))) void*)g,
                (__attribute__((address_space(3))) void*)(ldsB + s * 16),
                16, 0, 0);
        }
        __syncthreads();   // vmcnt(0) drain before barrier

#pragma unroll
        for (int ni = 0; ni < 4; ++ni) {
            // B-layout: n = lane&15 (local row R), k = (lane>>4)*32 + j
            const int R  = ni * 16 + l15;
            const int c0 = lg * 2;
            const int p0 = R * 8 + (c0 ^ (R & 7));
            const int p1 = R * 8 + ((c0 + 1) ^ (R & 7));
            intx4 blo = *reinterpret_cast<const intx4*>(ldsB + p0 * 16);
            intx4 bhi = *reinterpret_cast<const intx4*>(ldsB + p1 * 16);
            intx8 bfrag;
            bfrag[0] = blo[0]; bfrag[1] = blo[1]; bfrag[2] = blo[2]; bfrag[3] = blo[3];
            bfrag[4] = bhi[0]; bfrag[5] = bhi[1]; bfrag[6] = bhi[2]; bfrag[7] = bhi[3];
#pragma unroll
            for (int mi = 0; mi < 4; ++mi) {
                floatx4 acc = {0.f, 0.f, 0.f, 0.f};
                acc = __builtin_amdgcn_mfma_scale_f32_16x16x128_f8f6f4(
                    afrag[mi], bfrag, acc, 0, 0, 0, SCL1, 0, SCL1);
                // C/D layout: col = lane&15, row = (lane>>4)*4 + reg
#pragma unroll
                for (int r = 0; r < 4; ++r)
                    rowsum[mi][r] += EXP2F(acc[r]);   // acc is already SCALE*sim
            }
        }
    }

    // Sum across the 16 column-lanes within each lane-group.
#pragma unroll
    for (int mi = 0; mi < 4; ++mi)
#pragma unroll
        for (int r = 0; r < 4; ++r) {
            float v = rowsum[mi][r];
            v += __shfl_xor(v, 1, 64);
            v += __shfl_xor(v, 2, 64);
            v += __shfl_xor(v, 4, 64);
            v += __shfl_xor(v, 8, 64);
            rowsum[mi][r] = v;
        }
    if (l15 == 0) {
#pragma unroll
        for (int mi = 0; mi < 4; ++mi)
#pragma unroll
            for (int r = 0; r < 4; ++r)
                partial[csp * TWO_B + rowbase + mi * 16 + lg * 4 + r] = rowsum[mi][r];
    }
}

// ---------------------------------------------------------------------------
// Kernel 3: per-row finalize (non-atomic). One wave per row:
//   pos = fp32 dot(n_r, n_partner); sq = ||fp8row||^2 (same bytes as MFMA
//   diagonal -> exact cancellation, already in exp2 domain);
//   S = sum_c partial[c][row] + 2^(SCALE*pos) - 2^sq; loss = log(S) - pos/T.
// ---------------------------------------------------------------------------
__global__ __launch_bounds__(256) void fk(const float* __restrict__ nf,
                                          const unsigned char* __restrict__ n8,
                                          const float* __restrict__ partial,
                                          float* __restrict__ rowloss) {
    const int w = threadIdx.x >> 6, lane = threadIdx.x & 63;
    const int row = blockIdx.x * 4 + w;
    const int partner = (row + 4096) & (TWO_B - 1);
    float2 a = reinterpret_cast<const float2*>(nf + row * CDIM)[lane];
    float2 b = reinterpret_cast<const float2*>(nf + partner * CDIM)[lane];
    float dot = a.x * b.x + a.y * b.y;
    float sq = 0.0f;
    if (lane < 32) {
        const int p = reinterpret_cast<const int*>(n8 + row * CDIM)[lane];
        const float f0 = __builtin_amdgcn_cvt_f32_fp8(p, 0);
        const float f1 = __builtin_amdgcn_cvt_f32_fp8(p, 1);
        const float f2 = __builtin_amdgcn_cvt_f32_fp8(p, 2);
        const float f3 = __builtin_amdgcn_cvt_f32_fp8(p, 3);
        sq = f0 * f0 + f1 * f1 + f2 * f2 + f3 * f3;
    }
    float ps = (lane < 16) ? partial[lane * TWO_B + row] : 0.0f;
#pragma unroll
    for (int m = 1; m < 64; m <<= 1) {
        dot += __shfl_xor(dot, m, 64);
        sq  += __shfl_xor(sq,  m, 64);
        ps  += __shfl_xor(ps,  m, 64);
    }
    if (lane == 0) {
        const float S = ps + EXP2F(dot * SCALE) - EXP2F(sq);
        rowloss[row] = __logf(S) - dot * INV_T;
    }
}

// ---------------------------------------------------------------------------
// Kernel 4: mean over 8192 row losses -> fp32 scalar.
// ---------------------------------------------------------------------------
__global__ __launch_bounds__(256) void rk(const float* __restrict__ rowloss,
                                          float* __restrict__ out) {
    const int tid = threadIdx.x;
    float s = 0.f;
    for (int i = tid; i < TWO_B; i += 256) s += rowloss[i];
#pragma unroll
    for (int m = 1; m < 64; m <<= 1) s += __shfl_xor(s, m, 64);
    __shared__ float acc[4];
    if ((tid & 63) == 0) acc[tid >> 6] = s;
    __syncthreads();
    if (tid == 0)
        out[0] = (acc[0] + acc[1] + acc[2] + acc[3]) * (1.0f / TWO_B);
}

extern "C" void kernel_launch(void* const* d_in, const int* in_sizes, int n_in,
                              void* d_out, int out_size, void* d_ws, size_t ws_size,
                              hipStream_t stream) {
    const float* zi = (const float*)d_in[0];
    const float* zj = (const float*)d_in[1];
    char* ws = (char*)d_ws;
    float*         nf      = (float*)ws;                                   // 4 MB
    unsigned char* n8      = (unsigned char*)(ws + (size_t)TWO_B * CDIM * 4);  // 1 MB
    float*         partial = (float*)(ws + (size_t)TWO_B * CDIM * 5);      // 512 KB
    float*         rowloss = (float*)(ws + (size_t)TWO_B * CDIM * 5 + (size_t)16 * TWO_B * 4);

    nk<<<TWO_B / 8, 256, 0, stream>>>(zi, zj, nf, n8);
    sk<<<dim3(32, 16), 256, 0, stream>>>(n8, partial);
    fk<<<TWO_B / 4, 256, 0, stream>>>(nf, n8, partial, rowloss);
    rk<<<1, 256, 0, stream>>>(rowloss, (float*)d_out);
}

// Round 6
// 78.039 us; speedup vs baseline: 1.6033x; 1.1302x over previous
//
#include <hip/hip_runtime.h>
#include <hip/hip_bf16.h>

typedef int   intx8   __attribute__((ext_vector_type(8)));
typedef int   intx4   __attribute__((ext_vector_type(4)));
typedef float floatx4 __attribute__((ext_vector_type(4)));

static constexpr int TWO_B = 8192;   // 2*B rows
static constexpr int CDIM  = 128;    // feature dim
// exp(x/T) = exp2(x * (1/T)/ln2), T = 0.5
#define SCALE 2.8853900817779268f
#define SQS   1.6986436f             // sqrt(SCALE): n8 rows pre-scaled by this,
                                     // so MFMA output is already in exp2 domain
#define INV_T 2.0f

#if __has_builtin(__builtin_amdgcn_exp2f)
#define EXP2F(x) __builtin_amdgcn_exp2f(x)
#else
#define EXP2F(x) exp2f(x)
#endif

// e8m0 scale byte 0x7F = 2^0 = 1.0 in all four byte slots
#define SCL1 0x7F7F7F7F

// ---------------------------------------------------------------------------
// Kernel 1: pair-structured normalize. One wave per pair r: lanes 0-31 hold
// zi[r] (float4 each), lanes 32-63 hold zj[r]. Computes per-half L2 norm,
// the fp32-exact positive dot (cross-half shuffle), fp8-e4m3 rows pre-scaled
// by sqrt(SCALE), and each row's self-sq from the STORED fp8 bytes (exact
// cancellation against the MFMA diagonal). No fp32 normalized buffer at all.
// ---------------------------------------------------------------------------
__global__ __launch_bounds__(256) void nk(const float* __restrict__ zi,
                                          const float* __restrict__ zj,
                                          unsigned char* __restrict__ n8,
                                          float* __restrict__ posv,
                                          float* __restrict__ sqv) {
    const int w = threadIdx.x >> 6, lane = threadIdx.x & 63;
    const int pr   = blockIdx.x * 4 + w;   // pair index 0..4095
    const int half = lane >> 5;            // 0: zi row, 1: zj row
    const int l32  = lane & 31;
    const float* src = half ? (zj + (size_t)pr * CDIM) : (zi + (size_t)pr * CDIM);
    float4 x = reinterpret_cast<const float4*>(src)[l32];
    float ss = x.x * x.x + x.y * x.y + x.z * x.z + x.w * x.w;
#pragma unroll
    for (int m = 1; m < 32; m <<= 1) ss += __shfl_xor(ss, m, 64);  // within-half
    const float rn = rsqrtf(ss);
    float4 y; y.x = x.x * rn; y.y = x.y * rn; y.z = x.z * rn; y.w = x.w * rn;

    // fp32-exact positive dot: pair each lane with its cross-half partner.
    const float qx = __shfl_xor(y.x, 32, 64);
    const float qy = __shfl_xor(y.y, 32, 64);
    const float qz = __shfl_xor(y.z, 32, 64);
    const float qw = __shfl_xor(y.w, 32, 64);
    float d = y.x * qx + y.y * qy + y.z * qz + y.w * qw;
#pragma unroll
    for (int m = 1; m < 32; m <<= 1) d += __shfl_xor(d, m, 64);    // within-half = full dot

    // fp8 row, pre-scaled so MFMA output is SCALE*sim.
    int p = __builtin_amdgcn_cvt_pk_fp8_f32(y.x * SQS, y.y * SQS, 0, false);
    p     = __builtin_amdgcn_cvt_pk_fp8_f32(y.z * SQS, y.w * SQS, p, true);
    const int row = pr + half * 4096;
    reinterpret_cast<int*>(n8 + (size_t)row * CDIM)[l32] = p;

    // self-sq from the stored bytes (already in exp2 domain).
    const float f0 = __builtin_amdgcn_cvt_f32_fp8(p, 0);
    const float f1 = __builtin_amdgcn_cvt_f32_fp8(p, 1);
    const float f2 = __builtin_amdgcn_cvt_f32_fp8(p, 2);
    const float f3 = __builtin_amdgcn_cvt_f32_fp8(p, 3);
    float sq = f0 * f0 + f1 * f1 + f2 * f2 + f3 * f3;
#pragma unroll
    for (int m = 1; m < 32; m <<= 1) sq += __shfl_xor(sq, m, 64);  // within-half

    if (l32 == 0) { posv[row] = d; sqv[row] = sq; }
}

// ---------------------------------------------------------------------------
// Kernel 2: per-row sum of 2^(SCALE*sim) over a 512-column slice, via
// MX-scaled fp8 MFMA (K=128 in ONE instruction, scales = 1.0).
// Block = 256 thr (4 waves), 256 rows/block (wave w -> rows w*64..+64,
// 4 m-subtiles; each B-frag feeds 4 MFMAs). Columns streamed in 64-wide
// stages (8 KB LDS) via global_load_lds 16B, global-side XOR swizzle.
// Grid (32,16); partials per (split,row); no atomics. [unchanged from R5]
// ---------------------------------------------------------------------------
__global__ __launch_bounds__(256) void sk(const unsigned char* __restrict__ n8,
                                          float* __restrict__ partial) {
    const int rt  = blockIdx.x;   // 0..31
    const int csp = blockIdx.y;   // 0..15
    const int tid = threadIdx.x;
    const int w   = tid >> 6;
    const int lane = tid & 63;
    const int l15 = lane & 15;
    const int lg  = lane >> 4;

    __shared__ unsigned char ldsB[64 * CDIM];   // 8 KB (fp8)

    // A fragments: 64 rows x 128 k per wave, registers.
    // f8f6f4 16x16x128 A-layout: m = lane&15, k = (lane>>4)*32 + j, j in [0,32)
    const int rowbase = rt * 256 + w * 64;
    intx8 afrag[4];
#pragma unroll
    for (int mi = 0; mi < 4; ++mi)
        afrag[mi] = *reinterpret_cast<const intx8*>(
            n8 + (size_t)(rowbase + mi * 16 + l15) * CDIM + lg * 32);

    float rowsum[4][4];
#pragma unroll
    for (int mi = 0; mi < 4; ++mi)
#pragma unroll
        for (int r = 0; r < 4; ++r) rowsum[mi][r] = 0.0f;

    const int colbase0 = csp * 512;
    for (int ct = 0; ct < 8; ++ct) {
        const int colbase = colbase0 + ct * 64;
        __syncthreads();   // previous stage's compute done before overwrite
        // Stage 64 rows x 128 B. LDS 16B-slot s holds global chunk
        // (R = s>>3, c = (s&7) ^ (R&7)) — swizzle on the global side.
#pragma unroll
        for (int i = 0; i < 2; ++i) {
            const int s = i * 256 + tid;          // uniform base + lane*16
            const int R = s >> 3, cs = s & 7;
            const int gc = cs ^ (R & 7);
            const unsigned char* g = n8 + (size_t)(colbase + R) * CDIM + gc * 16;
            __builtin_amdgcn_global_load_lds(
                (__attribute__((address_space(1))) void*)g,
                (__attribute__((address_space(3))) void*)(ldsB + s * 16),
                16, 0, 0);
        }
        __syncthreads();   // vmcnt(0) drain before barrier

#pragma unroll
        for (int ni = 0; ni < 4; ++ni) {
            // B-layout: n = lane&15 (local row R), k = (lane>>4)*32 + j
            const int R  = ni * 16 + l15;
            const int c0 = lg * 2;
            const int p0 = R * 8 + (c0 ^ (R & 7));
            const int p1 = R * 8 + ((c0 + 1) ^ (R & 7));
            intx4 blo = *reinterpret_cast<const intx4*>(ldsB + p0 * 16);
            intx4 bhi = *reinterpret_cast<const intx4*>(ldsB + p1 * 16);
            intx8 bfrag;
            bfrag[0] = blo[0]; bfrag[1] = blo[1]; bfrag[2] = blo[2]; bfrag[3] = blo[3];
            bfrag[4] = bhi[0]; bfrag[5] = bhi[1]; bfrag[6] = bhi[2]; bfrag[7] = bhi[3];
#pragma unroll
            for (int mi = 0; mi < 4; ++mi) {
                floatx4 acc = {0.f, 0.f, 0.f, 0.f};
                acc = __builtin_amdgcn_mfma_scale_f32_16x16x128_f8f6f4(
                    afrag[mi], bfrag, acc, 0, 0, 0, SCL1, 0, SCL1);
                // C/D layout: col = lane&15, row = (lane>>4)*4 + reg
#pragma unroll
                for (int r = 0; r < 4; ++r)
                    rowsum[mi][r] += EXP2F(acc[r]);   // acc is already SCALE*sim
            }
        }
    }

    // Sum across the 16 column-lanes within each lane-group.
#pragma unroll
    for (int mi = 0; mi < 4; ++mi)
#pragma unroll
        for (int r = 0; r < 4; ++r) {
            float v = rowsum[mi][r];
            v += __shfl_xor(v, 1, 64);
            v += __shfl_xor(v, 2, 64);
            v += __shfl_xor(v, 4, 64);
            v += __shfl_xor(v, 8, 64);
            rowsum[mi][r] = v;
        }
    if (l15 == 0) {
#pragma unroll
        for (int mi = 0; mi < 4; ++mi)
#pragma unroll
            for (int r = 0; r < 4; ++r)
                partial[csp * TWO_B + rowbase + mi * 16 + lg * 4 + r] = rowsum[mi][r];
    }
}

// ---------------------------------------------------------------------------
// Kernel 3: thread-per-row finalize. 32 blocks x 256 rows:
//   S = sum_c partial[c][row] + 2^(SCALE*pos) - 2^sq
//   loss_r = ln(S) - pos/T;  block-reduce 256 losses -> blocksum[32].
// ---------------------------------------------------------------------------
__global__ __launch_bounds__(256) void fk(const float* __restrict__ partial,
                                          const float* __restrict__ posv,
                                          const float* __restrict__ sqv,
                                          float* __restrict__ blocksum) {
    const int row = blockIdx.x * 256 + threadIdx.x;
    float S = 0.0f;
#pragma unroll
    for (int c = 0; c < 16; ++c) S += partial[c * TWO_B + row];
    const float pos = posv[row], sq = sqv[row];
    S += EXP2F(pos * SCALE) - EXP2F(sq);
    float loss = __logf(S) - pos * INV_T;
#pragma unroll
    for (int m = 1; m < 64; m <<= 1) loss += __shfl_xor(loss, m, 64);
    __shared__ float acc[4];
    if ((threadIdx.x & 63) == 0) acc[threadIdx.x >> 6] = loss;
    __syncthreads();
    if (threadIdx.x == 0)
        blocksum[blockIdx.x] = acc[0] + acc[1] + acc[2] + acc[3];
}

// ---------------------------------------------------------------------------
// Kernel 4: reduce 32 block sums -> fp32 mean. Single wave.
// ---------------------------------------------------------------------------
__global__ __launch_bounds__(64) void rk(const float* __restrict__ blocksum,
                                         float* __restrict__ out) {
    float s = (threadIdx.x < 32) ? blocksum[threadIdx.x] : 0.0f;
#pragma unroll
    for (int m = 1; m < 64; m <<= 1) s += __shfl_xor(s, m, 64);
    if (threadIdx.x == 0) out[0] = s * (1.0f / TWO_B);
}

extern "C" void kernel_launch(void* const* d_in, const int* in_sizes, int n_in,
                              void* d_out, int out_size, void* d_ws, size_t ws_size,
                              hipStream_t stream) {
    const float* zi = (const float*)d_in[0];
    const float* zj = (const float*)d_in[1];
    char* ws = (char*)d_ws;
    unsigned char* n8       = (unsigned char*)ws;                        // 1 MB
    float*         partial  = (float*)(ws + (size_t)TWO_B * CDIM);       // 512 KB
    float*         posv     = (float*)(ws + (size_t)TWO_B * CDIM + 16 * TWO_B * 4);
    float*         sqv      = posv + TWO_B;                              // 32 KB each
    float*         blocksum = sqv + TWO_B;                               // 128 B

    nk<<<TWO_B / 8, 256, 0, stream>>>(zi, zj, n8, posv, sqv);
    sk<<<dim3(32, 16), 256, 0, stream>>>(n8, partial);
    fk<<<32, 256, 0, stream>>>(partial, posv, sqv, blocksum);
    rk<<<1, 64, 0, stream>>>(blocksum, (float*)d_out);
}